// Round 12
// baseline (123.105 us; speedup 1.0000x reference)
//
#include <hip/hip_runtime.h>
#include <hip/hip_bf16.h>
#include <math.h>

#define B_DIM 8192
#define IN_F  1024
#define OUT_F 1024
#define NSTEP 160                    // 32 g-groups x 5 slabs (K=5120)
#define BTILE 8192                   // one step-tile: 128 rows/cols x 32 k x 2B

typedef unsigned short u16;
typedef unsigned int u32;
typedef __attribute__((ext_vector_type(8))) short bf16x8;
typedef __attribute__((ext_vector_type(8))) unsigned short u16x8;
typedef __attribute__((ext_vector_type(4))) float f32x4;

#define GLOBAL_AS __attribute__((address_space(1)))
#define LDS_AS    __attribute__((address_space(3)))

__device__ __forceinline__ void gload16(const void* g, void* l) {
    __builtin_amdgcn_global_load_lds((const GLOBAL_AS unsigned int*)g,
                                     (LDS_AS unsigned int*)l, 16, 0, 0);
}

__device__ __forceinline__ u16 f2bf(float v) {
    u32 u = __float_as_uint(v);
    return (u16)((u + 0x7FFFu + ((u >> 16) & 1u)) >> 16);
}

__device__ __forceinline__ u32 cvt_pk(float lo, float hi) {
    u32 r;
    asm("v_cvt_pk_bf16_f32 %0, %1, %2" : "=v"(r) : "v"(lo), "v"(hi));
    return r;
}

// ---------------------------------------------------------------------------
// bias[o] = sum_i sw[o,i,0]; plus 4 x-space step thresholds: smallest f32 T
// with (x >= T) <=> ((double)x > atanh(midpoint(grid[s], prevfloat(grid[s])))),
// replicating a correctly-rounded tanh's interval comparisons.
// ---------------------------------------------------------------------------
__global__ __launch_bounds__(256) void bias_thresh_kernel(
    const float* __restrict__ sw, const float* __restrict__ grid,
    float* __restrict__ biasT)
{
    int o    = blockIdx.x * 4 + (threadIdx.x >> 6);
    int lane = threadIdx.x & 63;
    float s = 0.f;
    #pragma unroll
    for (int j = 0; j < 16; ++j)
        s += sw[((size_t)o * IN_F + j * 64 + lane) * 8];
    #pragma unroll
    for (int off = 32; off; off >>= 1)
        s += __shfl_down(s, off);
    if (lane == 0) biasT[o] = s;

    if (blockIdx.x == 0 && threadIdx.x == 0) {
        #pragma unroll
        for (int k = 0; k < 4; ++k) {
            float gv = grid[k + 1];                 // -0.6, -0.2, 0.2, 0.6
            float below = nextafterf(gv, -2.0f);
            double mid = 0.5 * ((double)gv + (double)below);
            double t = atanh(mid);
            float Tf = (float)t;
            if (!((double)Tf > t)) Tf = nextafterf(Tf, 3.0f);
            biasT[1024 + k] = Tf;
        }
    }
}

// ---------------------------------------------------------------------------
// pack_A: 64 panels of 128 rows; tiles ordered t = g*5 + s.
//   s=0: bf16(x); s=1..4: 1[x >= T_s] as bf16 {0,1}.
// Tile byte = ((p*160 + t)*8192) + sm*1024 + lane*16.
// ---------------------------------------------------------------------------
__global__ __launch_bounds__(256) void pack_A_kernel(
    const float* __restrict__ x, const float* __restrict__ biasT,
    char* __restrict__ A)
{
    int gid  = blockIdx.x * 256 + threadIdx.x;      // 1,048,576 threads
    int lane = gid & 63;
    int wav  = gid >> 6;                            // 16384 waves
    int g    = wav & 31;
    int sm   = (wav >> 5) & 7;
    int p    = wav >> 8;                            // 0..63
    int fr   = lane & 15;
    int q    = lane >> 4;

    float T1 = biasT[1024], T2 = biasT[1025], T3 = biasT[1026], T4 = biasT[1027];

    int b  = p * 128 + sm * 16 + fr;
    int i0 = g * 32 + q * 8;

    const float* xr = x + (size_t)b * IN_F + i0;
    float4 a0 = *(const float4*)xr;
    float4 a1 = *(const float4*)(xr + 4);
    float v[8] = {a0.x, a0.y, a0.z, a0.w, a1.x, a1.y, a1.z, a1.w};

    size_t tb = ((size_t)(p * NSTEP + g * 5)) * BTILE
              + (size_t)sm * 1024 + (size_t)lane * 16;

    {
        union { u32 u[4]; u16x8 s; } w;
        #pragma unroll
        for (int j = 0; j < 4; ++j) w.u[j] = cvt_pk(v[2 * j], v[2 * j + 1]);
        *(u16x8*)(A + tb) = w.s;
    }
    float T[4] = {T1, T2, T3, T4};
    #pragma unroll
    for (int s = 0; s < 4; ++s) {
        union { u32 u[4]; u16x8 t; } o;
        #pragma unroll
        for (int j = 0; j < 4; ++j)
            o.u[j] = (v[2 * j]     >= T[s] ? 0x00003F80u : 0u)
                   | (v[2 * j + 1] >= T[s] ? 0x3F800000u : 0u);
        *(u16x8*)(A + tb + (size_t)(s + 1) * BTILE) = o.t;
    }
}

// ---------------------------------------------------------------------------
// pack_B: 8 panels of 128 cols; tiles ordered t = g*5 + s.
//   s=0: bf16(base_weight); s=1..4: bf16(sw_s - sw_{s-1}).
// ---------------------------------------------------------------------------
__global__ __launch_bounds__(256) void pack_B_kernel(
    const float* __restrict__ sw, const float* __restrict__ bw,
    char* __restrict__ Bt)
{
    int gid  = blockIdx.x * 256 + threadIdx.x;      // 131072 threads
    int lane = gid & 63;
    int wav  = gid >> 6;                            // 2048 waves
    int g    = wav & 31;
    int sn   = (wav >> 5) & 7;
    int p    = wav >> 8;                            // 0..7
    int fc   = lane & 15;
    int q    = lane >> 4;

    int o  = p * 128 + sn * 16 + fc;
    int i0 = g * 32 + q * 8;

    size_t tb = ((size_t)(p * NSTEP + g * 5)) * BTILE
              + (size_t)sn * 1024 + (size_t)lane * 16;

    const float* bwr = bw + (size_t)o * IN_F + i0;
    float4 b0 = *(const float4*)bwr;
    float4 b1 = *(const float4*)(bwr + 4);
    float v[8] = {b0.x, b0.y, b0.z, b0.w, b1.x, b1.y, b1.z, b1.w};
    u16x8 s0;
    #pragma unroll
    for (int j = 0; j < 8; ++j) s0[j] = f2bf(v[j]);
    *(u16x8*)(Bt + tb) = s0;                        // s = 0

    float c[8][5];
    #pragma unroll
    for (int j = 0; j < 8; ++j) {
        const float* swr = sw + ((size_t)o * IN_F + i0 + j) * 8;
        float4 lo = *(const float4*)swr;
        float4 hi = *(const float4*)(swr + 4);
        c[j][0] = lo.x; c[j][1] = lo.y; c[j][2] = lo.z;
        c[j][3] = lo.w; c[j][4] = hi.x;
    }
    #pragma unroll
    for (int s = 1; s < 5; ++s) {
        u16x8 d;
        #pragma unroll
        for (int j = 0; j < 8; ++j) d[j] = f2bf(c[j][s] - c[j][s - 1]);
        *(u16x8*)(Bt + tb + (size_t)s * BTILE) = d;
    }
}

// ---------------------------------------------------------------------------
// GEMM: C = A @ B^T + bias. 128x128 tile, 160 step-tiles of BK=32.
// B: 4-slot LDS ring via global_load_lds (writes 8KB/tile/block).
// A: direct global->register fragments, double-buffered (afA/afB), 1 tile
//    ahead; each frag is one coalesced dwordx4 per lane from the pre-tiled
//    image. LDS traffic halves vs R11 (96->48 KB/CU/tile).
// Counted vmcnt queue (6 ops/iter = 2 stage + 4 afrag):
//   top of iter: WAITV(8) covers B(t); after issue: WAITV(6) covers af(t).
// 4 waves 2x2; wave = 64x64 out = 4x4 frags of 16x16.
// ---------------------------------------------------------------------------
#define WAITV(N) asm volatile("s_waitcnt vmcnt(" #N ")" ::: "memory")

__device__ __forceinline__ void load_afrag(const char* aw, int t, bf16x8 af[4]) {
    const char* p = aw + (size_t)t * BTILE;
    af[0] = *(const bf16x8*)(p);
    af[1] = *(const bf16x8*)(p + 1024);
    af[2] = *(const bf16x8*)(p + 2048);
    af[3] = *(const bf16x8*)(p + 3072);
}

__device__ __forceinline__ void mfma16(const char* slot, int wc, int lane,
                                       const bf16x8 af[4], f32x4 acc[4][4]) {
    bf16x8 bf[4];
    #pragma unroll
    for (int n = 0; n < 4; ++n)
        bf[n] = *(const bf16x8*)(slot + (wc * 4 + n) * 1024 + lane * 16);
    __builtin_amdgcn_s_setprio(1);
    #pragma unroll
    for (int m = 0; m < 4; ++m)
        #pragma unroll
        for (int n = 0; n < 4; ++n)
            acc[m][n] = __builtin_amdgcn_mfma_f32_16x16x32_bf16(
                af[m], bf[n], acc[m][n], 0, 0, 0);
    __builtin_amdgcn_s_setprio(0);
}

__global__ __launch_bounds__(256, 2) void gemm_kernel(
    const char* __restrict__ At, const char* __restrict__ Bt,
    const float* __restrict__ biasT, float* __restrict__ C)
{
    __shared__ __align__(16) char lds[4 * BTILE];   // B-only ring, 32 KB

    int tid = threadIdx.x;
    int bid = blockIdx.x;                           // 0..511

    // XCD swizzle: each XCD owns 8 brow-panels x all 8 bcols -> A-panel
    // shared by 8 same-XCD blocks (L2 reuse proven by R11 FETCH=82MB).
    int xcd  = bid & 7;
    int slot = bid >> 3;
    int tile = xcd * 64 + slot;
    int brow = tile >> 3;                           // 0..63
    int bcol = tile & 7;                            // 0..7

    int lane = tid & 63;
    int w    = tid >> 6;
    int wr   = w >> 1;
    int wc   = w & 1;

    const char* aw = At + (size_t)brow * NSTEP * BTILE
                   + (size_t)(wr * 4) * 1024 + (size_t)lane * 16;
    const char* sp = Bt + (size_t)bcol * NSTEP * BTILE + (size_t)tid * 16;
    char*     sdst = lds + (size_t)tid * 16;

    int ccol0 = bcol * 128 + wc * 64 + (lane & 15);

    f32x4 acc[4][4];
    #pragma unroll
    for (int n = 0; n < 4; ++n) {
        float bv = biasT[ccol0 + n * 16];
        #pragma unroll
        for (int m = 0; m < 4; ++m)
            #pragma unroll
            for (int j = 0; j < 4; ++j)
                acc[m][n][j] = bv;
    }

    #define STAGE_B(T) do {                                                   \
        const char* _s = sp + (size_t)(T) * BTILE;                            \
        char* _d = sdst + ((T) & 3) * BTILE;                                  \
        gload16(_s, _d); gload16(_s + 4096, _d + 4096);                       \
    } while (0)

    bf16x8 afA[4], afB[4];

    // prologue: B(0),B(1),B(2) staged (6 ops) + af(0) (4 ops) = 10 in flight
    STAGE_B(0); STAGE_B(1); STAGE_B(2);
    load_afrag(aw, 0, afA);

    // steady-state iter: [WAITV(8); barrier; stage B(t+3); load af(t+1);
    //                     WAITV(6); sched_barrier; bf reads + 16 MFMA]
    #define ITER_FULL(T, CUR, NXT) do {                                       \
        WAITV(8); __builtin_amdgcn_s_barrier();                               \
        STAGE_B((T) + 3);                                                     \
        load_afrag(aw, (T) + 1, NXT);                                         \
        __builtin_amdgcn_sched_barrier(0);                                    \
        WAITV(6);                                                             \
        __builtin_amdgcn_sched_barrier(0);                                    \
        mfma16(lds + ((T) & 3) * BTILE, wc, lane, CUR, acc);                  \
    } while (0)

    #pragma unroll 1
    for (int t = 0; t < 156; t += 2) {
        ITER_FULL(t,     afA, afB);
        ITER_FULL(t + 1, afB, afA);
    }
    ITER_FULL(156, afA, afB);                       // stages B(159), af(157)

    // t = 157: no stage left; load af(158)
    WAITV(8); __builtin_amdgcn_s_barrier();
    load_afrag(aw, 158, afA);
    __builtin_amdgcn_sched_barrier(0);
    WAITV(4);
    __builtin_amdgcn_sched_barrier(0);
    mfma16(lds + (157 & 3) * BTILE, wc, lane, afB, acc);

    // t = 158: load af(159)
    WAITV(4); __builtin_amdgcn_s_barrier();
    load_afrag(aw, 159, afB);
    __builtin_amdgcn_sched_barrier(0);
    WAITV(4);
    __builtin_amdgcn_sched_barrier(0);
    mfma16(lds + (158 & 3) * BTILE, wc, lane, afA, acc);

    // t = 159
    WAITV(4); __builtin_amdgcn_s_barrier();
    WAITV(0);
    __builtin_amdgcn_sched_barrier(0);
    mfma16(lds + (159 & 3) * BTILE, wc, lane, afB, acc);

    #undef ITER_FULL
    #undef STAGE_B

    // epilogue: C/D layout col = lane&15, row = (lane>>4)*4 + reg (bias in acc)
    int crow0 = brow * 128 + wr * 64 + ((lane >> 4) << 2);
    #pragma unroll
    for (int m = 0; m < 4; ++m)
        #pragma unroll
        for (int j = 0; j < 4; ++j) {
            size_t r = (size_t)(crow0 + m * 16 + j);
            float* cp = C + r * OUT_F + ccol0;
            #pragma unroll
            for (int n = 0; n < 4; ++n)
                cp[n * 16] = acc[m][n][j];
        }
}

// Fallback signal if workspace is too small: absmax will read ~12345.
__global__ void sentinel_kernel(float* out, int n) {
    int i = blockIdx.x * 256 + threadIdx.x;
    if (i < n) out[i] = (i == 0) ? 12345.0f : 0.0f;
}

extern "C" void kernel_launch(void* const* d_in, const int* in_sizes, int n_in,
                              void* d_out, int out_size, void* d_ws, size_t ws_size,
                              hipStream_t stream) {
    const float* x    = (const float*)d_in[0];
    const float* sw   = (const float*)d_in[1];
    const float* bw   = (const float*)d_in[2];
    const float* grid = (const float*)d_in[3];
    float* out = (float*)d_out;

    const size_t A_bytes = (size_t)64 * NSTEP * BTILE;  // 83,886,080
    const size_t B_bytes = (size_t)8  * NSTEP * BTILE;  // 10,485,760
    const size_t bias_bytes = (1024 + 4) * sizeof(float);
    if (ws_size < A_bytes + B_bytes + bias_bytes) {
        sentinel_kernel<<<(out_size + 255) / 256, 256, 0, stream>>>(out, out_size);
        return;
    }

    char*  At    = (char*)d_ws;
    char*  Bt    = (char*)d_ws + A_bytes;
    float* biasT = (float*)((char*)d_ws + A_bytes + B_bytes);

    bias_thresh_kernel<<<256, 256, 0, stream>>>(sw, grid, biasT);
    pack_A_kernel<<<4096, 256, 0, stream>>>(x, biasT, At);
    pack_B_kernel<<<512, 256, 0, stream>>>(sw, bw, Bt);
    gemm_kernel<<<512, 256, 0, stream>>>(At, Bt, biasT, out);
}

// Round 13
// 108.026 us; speedup vs baseline: 1.1396x; 1.1396x over previous
//
#include <hip/hip_runtime.h>
#include <hip/hip_bf16.h>
#include <math.h>

#define B_DIM 8192
#define IN_F  1024
#define OUT_F 1024
#define NSTEP 160                    // 32 g-groups x 5 slabs (K=5120)
#define BTILE 8192                   // one step-tile: 128 rows/cols x 32 k x 2B

typedef unsigned short u16;
typedef unsigned int u32;
typedef __attribute__((ext_vector_type(8))) short bf16x8;
typedef __attribute__((ext_vector_type(8))) unsigned short u16x8;
typedef __attribute__((ext_vector_type(4))) float f32x4;

#define GLOBAL_AS __attribute__((address_space(1)))
#define LDS_AS    __attribute__((address_space(3)))

__device__ __forceinline__ void gload16(const void* g, void* l) {
    __builtin_amdgcn_global_load_lds((const GLOBAL_AS unsigned int*)g,
                                     (LDS_AS unsigned int*)l, 16, 0, 0);
}

__device__ __forceinline__ u16 f2bf(float v) {
    u32 u = __float_as_uint(v);
    return (u16)((u + 0x7FFFu + ((u >> 16) & 1u)) >> 16);
}

__device__ __forceinline__ u32 cvt_pk(float lo, float hi) {
    u32 r;
    asm("v_cvt_pk_bf16_f32 %0, %1, %2" : "=v"(r) : "v"(lo), "v"(hi));
    return r;
}

// x-space step threshold for grid value gv: smallest f32 T with
// (x >= T) <=> ((double)x > atanh(midpoint(gv, prevfloat(gv)))) —
// replicates a correctly-rounded tanh's interval comparisons.
__device__ __forceinline__ float step_threshold(float gv) {
    float below = nextafterf(gv, -2.0f);
    double mid = 0.5 * ((double)gv + (double)below);
    double t = atanh(mid);
    float Tf = (float)t;
    if (!((double)Tf > t)) Tf = nextafterf(Tf, 3.0f);
    return Tf;
}

// ---------------------------------------------------------------------------
// prep kernel — one launch, three sections by blockIdx:
//   bid 0..511    : pack_B  (8 panels x 128 cols; s=0 base_weight,
//                   s=1..4 bf16(sw_s - sw_{s-1}); tiles t = g*5 + s)
//   bid 512..767  : bias[o] = sum_i sw[o,i,0]  (f32, exact)
//   bid 768..4863 : pack_A  (64 panels x 128 rows; s=0 bf16(x),
//                   s=1..4 step indicators 1[x >= T_s]; per-block thresholds)
// Short sections dispatch first so they stream under pack_A.
// Tile byte = ((panel*160 + t)*8192) + sub*1024 + lane*16 for both images.
// ---------------------------------------------------------------------------
__global__ __launch_bounds__(256) void prep_kernel(
    const float* __restrict__ x, const float* __restrict__ sw,
    const float* __restrict__ bw, const float* __restrict__ grid,
    char* __restrict__ At, char* __restrict__ Bt, float* __restrict__ biasT)
{
    int bid = blockIdx.x;
    int tid = threadIdx.x;

    if (bid < 512) {                                // ---- pack_B ----
        int gid  = bid * 256 + tid;
        int lane = gid & 63;
        int wav  = gid >> 6;
        int g    = wav & 31;
        int sn   = (wav >> 5) & 7;
        int p    = wav >> 8;                        // 0..7
        int fc   = lane & 15;
        int q    = lane >> 4;

        int o  = p * 128 + sn * 16 + fc;
        int i0 = g * 32 + q * 8;

        size_t tb = ((size_t)(p * NSTEP + g * 5)) * BTILE
                  + (size_t)sn * 1024 + (size_t)lane * 16;

        const float* bwr = bw + (size_t)o * IN_F + i0;
        float4 b0 = *(const float4*)bwr;
        float4 b1 = *(const float4*)(bwr + 4);
        float v[8] = {b0.x, b0.y, b0.z, b0.w, b1.x, b1.y, b1.z, b1.w};
        u16x8 s0;
        #pragma unroll
        for (int j = 0; j < 8; ++j) s0[j] = f2bf(v[j]);
        *(u16x8*)(Bt + tb) = s0;                    // s = 0

        float c[8][5];
        #pragma unroll
        for (int j = 0; j < 8; ++j) {
            const float* swr = sw + ((size_t)o * IN_F + i0 + j) * 8;
            float4 lo = *(const float4*)swr;
            float4 hi = *(const float4*)(swr + 4);
            c[j][0] = lo.x; c[j][1] = lo.y; c[j][2] = lo.z;
            c[j][3] = lo.w; c[j][4] = hi.x;
        }
        #pragma unroll
        for (int s = 1; s < 5; ++s) {
            u16x8 d;
            #pragma unroll
            for (int j = 0; j < 8; ++j) d[j] = f2bf(c[j][s] - c[j][s - 1]);
            *(u16x8*)(Bt + tb + (size_t)s * BTILE) = d;
        }
    } else if (bid < 768) {                         // ---- bias ----
        int o    = (bid - 512) * 4 + (tid >> 6);
        int lane = tid & 63;
        float s = 0.f;
        #pragma unroll
        for (int j = 0; j < 16; ++j)
            s += sw[((size_t)o * IN_F + j * 64 + lane) * 8];
        #pragma unroll
        for (int off = 32; off; off >>= 1)
            s += __shfl_down(s, off);
        if (lane == 0) biasT[o] = s;
    } else {                                        // ---- pack_A ----
        __shared__ float thr[4];
        if (tid == 0) {
            #pragma unroll
            for (int k = 0; k < 4; ++k)
                thr[k] = step_threshold(grid[k + 1]);   // -0.6,-0.2,0.2,0.6
        }
        __syncthreads();
        float T1 = thr[0], T2 = thr[1], T3 = thr[2], T4 = thr[3];

        int gid  = (bid - 768) * 256 + tid;         // 0 .. 1,048,575
        int lane = gid & 63;
        int wav  = gid >> 6;
        int g    = wav & 31;
        int sm   = (wav >> 5) & 7;
        int p    = wav >> 8;                        // 0..63
        int fr   = lane & 15;
        int q    = lane >> 4;

        int b  = p * 128 + sm * 16 + fr;
        int i0 = g * 32 + q * 8;

        const float* xr = x + (size_t)b * IN_F + i0;
        float4 a0 = *(const float4*)xr;
        float4 a1 = *(const float4*)(xr + 4);
        float v[8] = {a0.x, a0.y, a0.z, a0.w, a1.x, a1.y, a1.z, a1.w};

        size_t tb = ((size_t)(p * NSTEP + g * 5)) * BTILE
                  + (size_t)sm * 1024 + (size_t)lane * 16;

        {
            union { u32 u[4]; u16x8 s; } wpk;
            #pragma unroll
            for (int j = 0; j < 4; ++j) wpk.u[j] = cvt_pk(v[2*j], v[2*j+1]);
            *(u16x8*)(At + tb) = wpk.s;             // s = 0: bf16(x)
        }
        float T[4] = {T1, T2, T3, T4};
        #pragma unroll
        for (int s = 0; s < 4; ++s) {
            union { u32 u[4]; u16x8 t; } o;
            #pragma unroll
            for (int j = 0; j < 4; ++j)
                o.u[j] = (v[2*j]     >= T[s] ? 0x00003F80u : 0u)
                       | (v[2*j + 1] >= T[s] ? 0x3F800000u : 0u);
            *(u16x8*)(At + tb + (size_t)(s + 1) * BTILE) = o.t;
        }
    }
}

// ---------------------------------------------------------------------------
// GEMM (R11 verbatim — measured 85.4us): C = A @ B^T + bias.
// 128x128 tile, 160 step-tiles of BK=32, 4-buffer LDS ring (64 KB),
// depth-3 prefetch, counted vmcnt (never 0 in steady state), one raw
// s_barrier per tile, setprio around MFMA cluster. 4 waves 2x2;
// wave = 64x64 out = 4x4 frags of 16x16.
// ---------------------------------------------------------------------------
__device__ __forceinline__ void stage_tile(const char* Ap, const char* Bp,
                                           int t, char* buf, int tid) {
    const char* sa = Ap + (size_t)t * BTILE;
    const char* sb = Bp + (size_t)t * BTILE;
    gload16(sa + tid * 16,        buf + tid * 16);
    gload16(sa + tid * 16 + 4096, buf + tid * 16 + 4096);
    gload16(sb + tid * 16,        buf + 8192 + tid * 16);
    gload16(sb + tid * 16 + 4096, buf + 8192 + tid * 16 + 4096);
}

__device__ __forceinline__ void compute_tile(const char* buf, int lane,
                                             int wr, int wc, f32x4 acc[4][4]) {
    const u16* As = (const u16*)buf;
    const u16* Bs = As + 4096;                      // +8192 bytes
    bf16x8 af[4], bfv[4];
    #pragma unroll
    for (int m = 0; m < 4; ++m)
        af[m] = *(const bf16x8*)(As + (wr * 4 + m) * 512 + lane * 8);
    #pragma unroll
    for (int n = 0; n < 4; ++n)
        bfv[n] = *(const bf16x8*)(Bs + (wc * 4 + n) * 512 + lane * 8);

    __builtin_amdgcn_s_setprio(1);
    #pragma unroll
    for (int m = 0; m < 4; ++m)
        #pragma unroll
        for (int n = 0; n < 4; ++n)
            acc[m][n] = __builtin_amdgcn_mfma_f32_16x16x32_bf16(
                af[m], bfv[n], acc[m][n], 0, 0, 0);
    __builtin_amdgcn_s_setprio(0);
}

__global__ __launch_bounds__(256, 2) void gemm_kernel(
    const char* __restrict__ At, const char* __restrict__ Bt,
    const float* __restrict__ biasT, float* __restrict__ C)
{
    __shared__ __align__(16) char lds[4 * 16384];   // 4-buffer ring, 64 KB

    int tid = threadIdx.x;
    int bid = blockIdx.x;                           // 0..511

    // XCD swizzle: each XCD owns an 8x8 supertile of output tiles.
    int xcd  = bid & 7;
    int slot = bid >> 3;
    int tile = xcd * 64 + slot;
    int brow = tile >> 3;                           // 0..63
    int bcol = tile & 7;                            // 0..7

    int lane = tid & 63;
    int w    = tid >> 6;
    int wr   = w >> 1;
    int wc   = w & 1;

    const char* Ap = At + (size_t)brow * NSTEP * BTILE;
    const char* Bp = Bt + (size_t)bcol * NSTEP * BTILE;

    int ccol0 = bcol * 128 + wc * 64 + (lane & 15);

    f32x4 acc[4][4];
    #pragma unroll
    for (int n = 0; n < 4; ++n) {
        float bv = biasT[ccol0 + n * 16];
        #pragma unroll
        for (int m = 0; m < 4; ++m)
            #pragma unroll
            for (int j = 0; j < 4; ++j)
                acc[m][n][j] = bv;
    }

    // prologue: fill 3 ring slots (12 loads in flight)
    stage_tile(Ap, Bp, 0, lds,          tid);
    stage_tile(Ap, Bp, 1, lds + 16384,  tid);
    stage_tile(Ap, Bp, 2, lds + 32768,  tid);

    for (int t = 0; t < NSTEP; ++t) {
        // wait for stage(t): leave later stages' loads in flight
        if (t < NSTEP - 2)       asm volatile("s_waitcnt vmcnt(8)" ::: "memory");
        else if (t == NSTEP - 2) asm volatile("s_waitcnt vmcnt(4)" ::: "memory");
        else                     asm volatile("s_waitcnt vmcnt(0)" ::: "memory");
        __builtin_amdgcn_s_barrier();               // publishes stage(t); fences
        asm volatile("" ::: "memory");              // compute(t-1) vs stage(t+3)

        if (t + 3 < NSTEP)
            stage_tile(Ap, Bp, t + 3, lds + ((t + 3) & 3) * 16384, tid);

        compute_tile(lds + (t & 3) * 16384, lane, wr, wc, acc);
    }

    // epilogue: C/D layout col = lane&15, row = (lane>>4)*4 + reg (bias in acc)
    int crow0 = brow * 128 + wr * 64 + ((lane >> 4) << 2);
    #pragma unroll
    for (int m = 0; m < 4; ++m)
        #pragma unroll
        for (int j = 0; j < 4; ++j) {
            size_t r = (size_t)(crow0 + m * 16 + j);
            float* cp = C + r * OUT_F + ccol0;
            #pragma unroll
            for (int n = 0; n < 4; ++n)
                cp[n * 16] = acc[m][n][j];
        }
}

// Fallback signal if workspace is too small: absmax will read ~12345.
__global__ void sentinel_kernel(float* out, int n) {
    int i = blockIdx.x * 256 + threadIdx.x;
    if (i < n) out[i] = (i == 0) ? 12345.0f : 0.0f;
}

extern "C" void kernel_launch(void* const* d_in, const int* in_sizes, int n_in,
                              void* d_out, int out_size, void* d_ws, size_t ws_size,
                              hipStream_t stream) {
    const float* x    = (const float*)d_in[0];
    const float* sw   = (const float*)d_in[1];
    const float* bw   = (const float*)d_in[2];
    const float* grid = (const float*)d_in[3];
    float* out = (float*)d_out;

    const size_t A_bytes = (size_t)64 * NSTEP * BTILE;  // 83,886,080
    const size_t B_bytes = (size_t)8  * NSTEP * BTILE;  // 10,485,760
    const size_t bias_bytes = 1024 * sizeof(float);
    if (ws_size < A_bytes + B_bytes + bias_bytes) {
        sentinel_kernel<<<(out_size + 255) / 256, 256, 0, stream>>>(out, out_size);
        return;
    }

    char*  At    = (char*)d_ws;
    char*  Bt    = (char*)d_ws + A_bytes;
    float* biasT = (float*)((char*)d_ws + A_bytes + B_bytes);

    prep_kernel<<<4864, 256, 0, stream>>>(x, sw, bw, grid, At, Bt, biasT);
    gemm_kernel<<<512, 256, 0, stream>>>(At, Bt, biasT, out);
}